// Round 13
// baseline (358.731 us; speedup 1.0000x reference)
//
#include <hip/hip_runtime.h>

// DQNet — MI355X (gfx950). ONE kernel, 256 blocks x 512 thr,
// per-GROUP atomic barriers (4 blocks/group) instead of grid.sync.
// Round-12 showed grid.sync costs ~38us each (8-XCD protocol); the h
// ping-pong only couples the 4 blocks of one group, so a 4-wide
// device-scope atomic barrier replaces it. Wt stays in LDS (no global Wt),
// base stays in registers. Counters zeroed via hipMemsetAsync (on-stream).
// Algebra (verified rounds 2-12):
//  - segment_sum over dense graph == n1 = Wt @ h, Wt[j][i]=e1^2*d, diag 0
//  - GNN step 1 has h=0  =>  h1 = relu(base + l2_b) exactly
//  - h2[a0]+h2[a1] == (h[a0]+h[a1])@t7_1_w + 2*t7_1_b
#define HD 64
#define NPG 100
#define NGRP 64
#define NACT 50
#define EPG 9900

typedef const float* fcp;

__device__ __forceinline__ void group_barrier(int* cnt) {
    __syncthreads();
    __threadfence();                    // release: this block's writes -> device
    if (threadIdx.x == 0) {
        atomicAdd(cnt, 1);
        while (__hip_atomic_load(cnt, __ATOMIC_ACQUIRE, __HIP_MEMORY_SCOPE_AGENT) < 4) {
            __builtin_amdgcn_s_sleep(1);
        }
    }
    __syncthreads();
    __threadfence();                    // acquire: invalidate stale cached lines
}

__global__ __launch_bounds__(512)
void k_fused(fcp label, fcp e_type, fcp dvec,
             fcp l1_w, fcp l1_b, fcp l2_w, fcp l2_b,
             fcp t3_w, fcp t3_b, fcp t4_w, fcp t4_b,
             fcp t5_w, fcp t5_b, fcp t6_w, fcp t6_b,
             fcp t7_1_w, fcp t7_1_b, fcp t7_2_w, fcp t7_2_b,
             fcp t9_1_w, fcp t9_1_b, fcp t9_2_w, fcp t9_2_b,
             const int* __restrict__ actions,
             int* __restrict__ cnts,
             float* __restrict__ hA, float* __restrict__ hB,
             float* __restrict__ out)
{
    const int g  = blockIdx.x >> 2;
    const int c  = blockIdx.x & 3;
    const int j0 = c * 25;
    const int t  = threadIdx.x;
    const int hh = t & 63;
    const int w  = t >> 6;              // wave 0..7

    __shared__ __align__(16) float wtc[2500];   // Wt chunk [jl*100+i], persistent A..C; hsum/r1s in D
    __shared__ __align__(16) float buf[6400];   // A..C: s_ld[0,2500)+aux[2500,4100) ; D: h3 slab
    __shared__ __align__(16) float awk[8 * HD]; // mean partials
    __shared__ float gbuf[HD];

    float* s_ld = buf;                  // 2500 floats
    float* aux  = buf + 2500;           // 1600 floats: t4s (A) / n1s (B,C)

    // ============ Phase A: edges -> Wt(LDS) + t4 -> base(regs) + h1 ============
    // prefetch label rows + l1_w (hides HBM latency behind staging)
    float lab[4][5], l1r[5];
    #pragma unroll
    for (int kk = 0; kk < 5; ++kk) l1r[kk] = l1_w[kk * HD + hh];
    #pragma unroll
    for (int m = 0; m < 4; ++m) {
        const int jl = w + 8 * m;
        #pragma unroll
        for (int kk = 0; kk < 5; ++kk)
            lab[m][kk] = (jl < 25) ? label[(g * NPG + j0 + jl) * 5 + kk] : 0.f;
    }
    {
        const float2* et2 = (const float2*)e_type;
        const int ebase = g * EPG;
        for (int idx = t; idx < 2500; idx += 512) {
            const int i  = idx / 25;
            const int jl = idx - i * 25;
            const int j  = j0 + jl;
            float s = 0.f, wv = 0.f;
            if (i != j) {
                const int e = ebase + i * 99 + j - (j > i ? 1 : 0);
                const float e1 = et2[e].x;
                const float dd = dvec[e];
                s  = dd * e1;
                wv = e1 * e1 * dd;
            }
            s_ld[jl * 100 + i] = s;
            wtc[jl * 100 + i] = wv;     // resident until phase D
        }
    }
    __syncthreads();

    const float w4  = t4_w[hh];
    const float b4  = t4_b[hh];
    const float rb4 = fmaxf(b4, 0.f);   // cancels spurious diagonal term
    #pragma unroll
    for (int m = 0; m < 4; ++m) {
        const int jl = w + 8 * m;
        if (jl < 25) {
            float a0 = 0.f, a1 = 0.f, a2 = 0.f, a3 = 0.f;
            #pragma unroll 5
            for (int ib = 0; ib < 25; ++ib) {
                const float4 s4 = *(const float4*)&s_ld[jl * 100 + 4 * ib];
                a0 += fmaxf(s4.x * w4 + b4, 0.f);
                a1 += fmaxf(s4.y * w4 + b4, 0.f);
                a2 += fmaxf(s4.z * w4 + b4, 0.f);
                a3 += fmaxf(s4.w * w4 + b4, 0.f);
            }
            aux[jl * HD + hh] = (a0 + a1) + (a2 + a3) - rb4;   // t4s, wave-local
        }
    }

    float base_r[4];
    {
        const float bb = l1_b[hh] + t3_b[hh];
        #pragma unroll
        for (int m = 0; m < 4; ++m) {
            float x = bb;
            #pragma unroll
            for (int kk = 0; kk < 5; ++kk) x += lab[m][kk] * l1r[kk];
            base_r[m] = x;
        }
        for (int ib = 0; ib < 16; ++ib) {   // q-outer: weights shared by rows
            const float tw0 = t3_w[(4 * ib + 0) * HD + hh];
            const float tw1 = t3_w[(4 * ib + 1) * HD + hh];
            const float tw2 = t3_w[(4 * ib + 2) * HD + hh];
            const float tw3 = t3_w[(4 * ib + 3) * HD + hh];
            #pragma unroll
            for (int m = 0; m < 4; ++m) {
                const int jl = w + 8 * m;
                if (jl < 25) {
                    const float4 x4 = *(const float4*)&aux[jl * HD + 4 * ib];
                    base_r[m] += x4.x * tw0 + x4.y * tw1 + x4.z * tw2 + x4.w * tw3;
                }
            }
        }
    }
    const float l2bv = l2_b[hh];
    #pragma unroll
    for (int m = 0; m < 4; ++m) {       // h1 = relu(base + l2_b)  (step 1, h0=0)
        const int jl = w + 8 * m;
        if (jl < 25) hA[(g * NPG + j0 + jl) * HD + hh] = fmaxf(base_r[m] + l2bv, 0.f);
    }
    group_barrier(&cnts[g * 3 + 0]);    // ---- group barrier 1 (h1 ready)

    // ============ Phases B,C: GNN steps 2,3 ============
    const float* hsrc = hA;
    float*       hdst = hB;
    for (int step = 0; step < 2; ++step) {
        // n1 = Wt(LDS) @ h(global; coalesced 256B row loads, L1-hot)
        const float* hgp = hsrc + g * NPG * HD + hh;
        float acc[4];
        #pragma unroll
        for (int m = 0; m < 4; ++m) acc[m] = 0.f;
        for (int ib = 0; ib < 25; ++ib) {
            const float h0 = hgp[(4 * ib + 0) * HD];
            const float h1 = hgp[(4 * ib + 1) * HD];
            const float h2 = hgp[(4 * ib + 2) * HD];
            const float h3 = hgp[(4 * ib + 3) * HD];
            #pragma unroll
            for (int m = 0; m < 4; ++m) {
                const int jl = w + 8 * m;
                if (jl < 25) {
                    const float4 wv = *(const float4*)&wtc[jl * 100 + 4 * ib];
                    acc[m] += wv.x * h0 + wv.y * h1 + wv.z * h2 + wv.w * h3;
                }
            }
        }
        #pragma unroll
        for (int m = 0; m < 4; ++m) {
            const int jl = w + 8 * m;
            if (jl < 25) aux[jl * HD + hh] = acc[m];      // n1, wave-local
        }
        // h' = relu(base + n1 @ l2_w + l2_b)
        float v[4];
        #pragma unroll
        for (int m = 0; m < 4; ++m) v[m] = base_r[m] + l2bv;
        for (int ib = 0; ib < 16; ++ib) {
            const float w0 = l2_w[(4 * ib + 0) * HD + hh];
            const float w1 = l2_w[(4 * ib + 1) * HD + hh];
            const float w2 = l2_w[(4 * ib + 2) * HD + hh];
            const float w3 = l2_w[(4 * ib + 3) * HD + hh];
            #pragma unroll
            for (int m = 0; m < 4; ++m) {
                const int jl = w + 8 * m;
                if (jl < 25) {
                    const float4 x4 = *(const float4*)&aux[jl * HD + 4 * ib];
                    v[m] += x4.x * w0 + x4.y * w1 + x4.z * w2 + x4.w * w3;
                }
            }
        }
        #pragma unroll
        for (int m = 0; m < 4; ++m) {
            const int jl = w + 8 * m;
            if (jl < 25) hdst[(g * NPG + j0 + jl) * HD + hh] = fmaxf(v[m], 0.f);
        }
        group_barrier(&cnts[g * 3 + 1 + step]);   // ---- barriers 2,3
        const float* tmp = hsrc; hsrc = hdst; hdst = (float*)tmp;
    }
    // h3 now in hA

    // ============ Phase D: tail (this block: 13 actions at c*13) ============
    const int a0g  = c * 13;
    const int acnt = (c < 3) ? 13 : 11;

    // prefetch action indices (waves 0-6 own rows al = w + 7m, m<2)
    int a0r[2], a1r[2];
    #pragma unroll
    for (int m = 0; m < 2; ++m) {
        const int al = w + 7 * m;
        a0r[m] = 0; a1r[m] = 0;
        if (w < 7 && al < acnt) {
            const int a = g * NACT + a0g + al;
            a0r[m] = actions[a * 2 + 0];
            a1r[m] = actions[a * 2 + 1];
        }
    }
    {   // stage h3 slab into buf (overwrites s_ld/aux)
        const float4* hg4 = (const float4*)(hA + g * NPG * HD);
        float4* hs4 = (float4*)buf;
        for (int idx = t; idx < NPG * HD / 4; idx += 512) hs4[idx] = hg4[idx];
    }
    __syncthreads();
    float* hsb  = buf;
    float* hsum = wtc;                  // Wt dead; 13*64=832 floats
    float* r1s  = wtc + 832;

    {   // mean partials (8 waves)
        float mm = 0.f;
        for (int j = w; j < NPG; j += 8) mm += hsb[j * HD + hh];
        awk[w * HD + hh] = mm;
    }
    #pragma unroll
    for (int m = 0; m < 2; ++m) {       // ha = h[a0]+h[a1] (wave-local rows)
        const int al = w + 7 * m;
        if (w < 7 && al < acnt)
            hsum[al * HD + hh] = hsb[a0r[m] * HD + hh] + hsb[a1r[m] * HD + hh];
    }
    __syncthreads();                    // awk ready for wave 7

    if (w == 7) {       // stem chain, concurrent with waves 0-6
        float ml = 0.f;
        #pragma unroll
        for (int ww = 0; ww < 8; ++ww) ml += awk[ww * HD + hh];
        ml *= (1.f / NPG);
        float s = t6_b[hh];
        #pragma unroll 8
        for (int q = 0; q < HD; ++q) s += __shfl(ml, q, 64) * t6_w[q * HD + hh];
        s = fmaxf(s, 0.f);
        float gb = t9_1_b[hh];
        #pragma unroll 8
        for (int q = 0; q < HD; ++q) gb += __shfl(s, q, 64) * t9_1_w[q * HD + hh];
        gbuf[hh] = gb;
    } else {
        // r1 = relu(ha @ t7_1_w + 2*b71)
        const float b71 = 2.f * t7_1_b[hh];
        float r[2];
        #pragma unroll
        for (int m = 0; m < 2; ++m) r[m] = b71;
        for (int ib = 0; ib < 16; ++ib) {
            const float w0 = t7_1_w[(4 * ib + 0) * HD + hh];
            const float w1 = t7_1_w[(4 * ib + 1) * HD + hh];
            const float w2 = t7_1_w[(4 * ib + 2) * HD + hh];
            const float w3 = t7_1_w[(4 * ib + 3) * HD + hh];
            #pragma unroll
            for (int m = 0; m < 2; ++m) {
                const int al = w + 7 * m;
                if (al < acnt) {
                    const float4 x4 = *(const float4*)&hsum[al * HD + 4 * ib];
                    r[m] += x4.x * w0 + x4.y * w1 + x4.z * w2 + x4.w * w3;
                }
            }
        }
        #pragma unroll
        for (int m = 0; m < 2; ++m) {
            const int al = w + 7 * m;
            if (al < acnt) r1s[al * HD + hh] = fmaxf(r[m], 0.f);
        }
        // r2 = relu(r1 @ t7_2_w + b72) -> hsum
        const float b72 = t7_2_b[hh];
        #pragma unroll
        for (int m = 0; m < 2; ++m) r[m] = b72;
        for (int ib = 0; ib < 16; ++ib) {
            const float w0 = t7_2_w[(4 * ib + 0) * HD + hh];
            const float w1 = t7_2_w[(4 * ib + 1) * HD + hh];
            const float w2 = t7_2_w[(4 * ib + 2) * HD + hh];
            const float w3 = t7_2_w[(4 * ib + 3) * HD + hh];
            #pragma unroll
            for (int m = 0; m < 2; ++m) {
                const int al = w + 7 * m;
                if (al < acnt) {
                    const float4 x4 = *(const float4*)&r1s[al * HD + 4 * ib];
                    r[m] += x4.x * w0 + x4.y * w1 + x4.z * w2 + x4.w * w3;
                }
            }
        }
        #pragma unroll
        for (int m = 0; m < 2; ++m) {
            const int al = w + 7 * m;
            if (al < acnt) hsum[al * HD + hh] = fmaxf(r[m], 0.f);
        }
    }
    __syncthreads();                    // gbuf ready

    if (w < 7) {
        // u = r2 @ t9_2_w + b92 ; q = relu(gb+u) ; Q = q . t5_w + t5_b
        const float b92  = t9_2_b[hh];
        const float t5wv = t5_w[hh];
        const float t5bv = t5_b[0];
        const float gbv  = gbuf[hh];
        float u[2];
        #pragma unroll
        for (int m = 0; m < 2; ++m) u[m] = b92;
        for (int ib = 0; ib < 16; ++ib) {
            const float w0 = t9_2_w[(4 * ib + 0) * HD + hh];
            const float w1 = t9_2_w[(4 * ib + 1) * HD + hh];
            const float w2 = t9_2_w[(4 * ib + 2) * HD + hh];
            const float w3 = t9_2_w[(4 * ib + 3) * HD + hh];
            #pragma unroll
            for (int m = 0; m < 2; ++m) {
                const int al = w + 7 * m;
                if (al < acnt) {
                    const float4 x4 = *(const float4*)&hsum[al * HD + 4 * ib];
                    u[m] += x4.x * w0 + x4.y * w1 + x4.z * w2 + x4.w * w3;
                }
            }
        }
        #pragma unroll
        for (int m = 0; m < 2; ++m) {
            const int al = w + 7 * m;
            float qv = fmaxf(gbv + u[m], 0.f) * t5wv;
            #pragma unroll
            for (int off = 32; off > 0; off >>= 1) qv += __shfl_xor(qv, off, 64);
            if (al < acnt && hh == 0) out[g * NACT + a0g + al] = qv + t5bv;
        }
    }
}

// ---------------------------------------------------------------------------
extern "C" void kernel_launch(void* const* d_in, const int* in_sizes, int n_in,
                              void* d_out, int out_size, void* d_ws, size_t ws_size,
                              hipStream_t stream)
{
    fcp label  = (fcp)d_in[0];
    fcp e_type = (fcp)d_in[1];
    fcp dvec   = (fcp)d_in[2];
    fcp l1_w   = (fcp)d_in[3];
    fcp l1_b   = (fcp)d_in[4];
    fcp l2_w   = (fcp)d_in[5];
    fcp l2_b   = (fcp)d_in[6];
    fcp t3_w   = (fcp)d_in[7];
    fcp t3_b   = (fcp)d_in[8];
    fcp t4_w   = (fcp)d_in[9];
    fcp t4_b   = (fcp)d_in[10];
    fcp t5_w   = (fcp)d_in[11];
    fcp t5_b   = (fcp)d_in[12];
    fcp t6_w   = (fcp)d_in[13];
    fcp t6_b   = (fcp)d_in[14];
    fcp t7_1_w = (fcp)d_in[15];
    fcp t7_1_b = (fcp)d_in[16];
    fcp t7_2_w = (fcp)d_in[17];
    fcp t7_2_b = (fcp)d_in[18];
    fcp t9_1_w = (fcp)d_in[19];
    fcp t9_1_b = (fcp)d_in[20];
    fcp t9_2_w = (fcp)d_in[21];
    fcp t9_2_b = (fcp)d_in[22];
    // d_in[23]=src, d_in[24]=dst -- topology derived analytically
    const int* actions = (const int*)d_in[25];

    // Workspace: cnts (192 ints, zeroed each call) | hA | hB
    char* ws = (char*)d_ws;
    int*   cnts = (int*)ws;
    float* hA   = (float*)(ws + 1024);
    float* hB   = (float*)(ws + 1024 + 1638400);
    float* outp = (float*)d_out;

    hipMemsetAsync(cnts, 0, NGRP * 3 * sizeof(int), stream);
    k_fused<<<dim3(NGRP * 4), dim3(512), 0, stream>>>(
        label, e_type, dvec, l1_w, l1_b, l2_w, l2_b, t3_w, t3_b, t4_w, t4_b,
        t5_w, t5_b, t6_w, t6_b, t7_1_w, t7_1_b, t7_2_w, t7_2_b,
        t9_1_w, t9_1_b, t9_2_w, t9_2_b, actions, cnts, hA, hB, outp);
}

// Round 14
// 171.180 us; speedup vs baseline: 2.0956x; 2.0956x over previous
//
#include <hip/hip_runtime.h>

// DQNet — MI355X (gfx950). 4-kernel split, 512-thread blocks (2 waves/SIMD).
// ROUND-14: restore round 9's exact configuration — the measured optimum
// (168 us total vs 182-359 for every variant tried in rounds 10-13):
//  - chunk variants (13-row, 256-thr): 182-183 us (h-slab staging duplication)
//  - single fused kernel: 143-154 us kernel but only 64 CUs usable
//  - cooperative grid.sync: ~38 us PER SYNC (8-XCD protocol) -> 304 us
//  - per-group atomic barrier: device-scope spin even worse -> 359 us
// Lesson: cross-block sync must stay at kernel-boundary granularity; the
// 4-kernel graph with 1-barrier kernels and wave-local LDS rows is the floor.
// Algebra (verified rounds 2-13):
//  - segment_sum over dense graph == n1 = Wt @ h, Wt[j][i]=e1^2*d, diag 0
//  - GNN step 1 has h=0  =>  h1 = relu(base + l2_b) exactly
//  - h2[a0]+h2[a1] == (h[a0]+h[a1])@t7_1_w + 2*t7_1_b
#define HD 64
#define NPG 100
#define NGRP 64
#define NACT 50
#define EPG 9900

typedef const float* fcp;

// ---------------------------------------------------------------------------
// K1: block = (group, 25-dst chunk), grid 256, 512 thr, ONE barrier.
// edges -> Wt (global) + t4 sums -> base + h1.
// ---------------------------------------------------------------------------
__global__ __launch_bounds__(512)
void k_edge_base(fcp label, fcp e_type, fcp dvec,
                 fcp l1_w, fcp l1_b, fcp l2_b,
                 fcp t3_w, fcp t3_b, fcp t4_w, fcp t4_b,
                 float* __restrict__ Wt, float* __restrict__ baseo,
                 float* __restrict__ hA)
{
    const int g  = blockIdx.x >> 2;
    const int c  = blockIdx.x & 3;
    const int j0 = c * 25;
    const int t  = threadIdx.x;
    const int hh = t & 63;
    const int w  = t >> 6;          // wave 0..7; rows jl = w + 8m (wave-local)

    __shared__ __align__(16) float s_ld[2500];      // [jl*100 + i]
    __shared__ __align__(16) float w_ld[2500];
    __shared__ __align__(16) float t4s[25 * HD];

    // prefetch label rows + l1_w (independent of staging; hides HBM latency)
    float lab[4][5], l1r[5];
    #pragma unroll
    for (int kk = 0; kk < 5; ++kk) l1r[kk] = l1_w[kk * HD + hh];
    #pragma unroll
    for (int m = 0; m < 4; ++m) {
        const int jl = w + 8 * m;
        #pragma unroll
        for (int kk = 0; kk < 5; ++kk)
            lab[m][kk] = (jl < 25) ? label[(g * NPG + j0 + jl) * 5 + kk] : 0.f;
    }

    const float2* et2 = (const float2*)e_type;
    const int ebase = g * EPG;
    // coalesced edge staging (consecutive t -> consecutive e), LDS transpose
    for (int idx = t; idx < 2500; idx += 512) {
        const int i  = idx / 25;
        const int jl = idx - i * 25;
        const int j  = j0 + jl;
        float s = 0.f, wv = 0.f;
        if (i != j) {
            const int e = ebase + i * 99 + j - (j > i ? 1 : 0);
            const float e1 = et2[e].x;
            const float dd = dvec[e];
            s  = dd * e1;
            wv = e1 * e1 * dd;
        }
        s_ld[jl * 100 + i] = s;
        w_ld[jl * 100 + i] = wv;
    }
    __syncthreads();        // the only barrier in K1

    {   // Wt global write: coalesced copy
        float* wd = Wt + g * (NPG * NPG) + j0 * NPG;
        for (int idx = t; idx < 2500; idx += 512) wd[idx] = w_ld[idx];
    }

    // t4 sums — wave-local rows, float4 broadcasts, 4 partial accumulators
    const float w4  = t4_w[hh];
    const float b4  = t4_b[hh];
    const float rb4 = fmaxf(b4, 0.f);       // cancels spurious diagonal term
    #pragma unroll
    for (int m = 0; m < 4; ++m) {
        const int jl = w + 8 * m;
        if (jl < 25) {
            float a0 = 0.f, a1 = 0.f, a2 = 0.f, a3 = 0.f;
            #pragma unroll 5
            for (int ib = 0; ib < 25; ++ib) {
                const float4 s4 = *(const float4*)&s_ld[jl * 100 + 4 * ib];
                a0 += fmaxf(s4.x * w4 + b4, 0.f);
                a1 += fmaxf(s4.y * w4 + b4, 0.f);
                a2 += fmaxf(s4.z * w4 + b4, 0.f);
                a3 += fmaxf(s4.w * w4 + b4, 0.f);
            }
            t4s[jl * HD + hh] = (a0 + a1) + (a2 + a3) - rb4;
        }
    }
    // no barrier: base matmul reads only this wave's own t4s rows

    const float bb   = l1_b[hh] + t3_b[hh];
    const float l2bv = l2_b[hh];
    float v[4];
    #pragma unroll
    for (int m = 0; m < 4; ++m) {
        float x = bb;
        #pragma unroll
        for (int kk = 0; kk < 5; ++kk) x += lab[m][kk] * l1r[kk];
        v[m] = x;
    }
    for (int ib = 0; ib < 16; ++ib) {       // q-outer: weight loads shared by rows
        const float tw0 = t3_w[(4 * ib + 0) * HD + hh];
        const float tw1 = t3_w[(4 * ib + 1) * HD + hh];
        const float tw2 = t3_w[(4 * ib + 2) * HD + hh];
        const float tw3 = t3_w[(4 * ib + 3) * HD + hh];
        #pragma unroll
        for (int m = 0; m < 4; ++m) {
            const int jl = w + 8 * m;
            if (jl < 25) {
                const float4 x4 = *(const float4*)&t4s[jl * HD + 4 * ib];
                v[m] += x4.x * tw0 + x4.y * tw1 + x4.z * tw2 + x4.w * tw3;
            }
        }
    }
    #pragma unroll
    for (int m = 0; m < 4; ++m) {
        const int jl = w + 8 * m;
        if (jl < 25) {
            const int n = g * NPG + j0 + jl;
            baseo[n * HD + hh] = v[m];
            hA[n * HD + hh]    = fmaxf(v[m] + l2bv, 0.f);   // GNN step 1 (h0=0)
        }
    }
}

// ---------------------------------------------------------------------------
// K2: one GNN step. block = (group, 25-dst chunk), grid 256, 512 thr.
// ONE barrier; base prefetched above staging.
// ---------------------------------------------------------------------------
__global__ __launch_bounds__(512)
void k_gnn_step(const float* __restrict__ Wt, const float* __restrict__ baseo,
                const float* __restrict__ h_old, fcp l2_w, fcp l2_b,
                float* __restrict__ h_new)
{
    const int g  = blockIdx.x >> 2;
    const int c  = blockIdx.x & 3;
    const int j0 = c * 25;
    const int t  = threadIdx.x;
    const int hh = t & 63;
    const int w  = t >> 6;          // wave 0..7

    __shared__ __align__(16) float hs[NPG * HD];    // 25.6 KB
    __shared__ __align__(16) float wr[2500];        // 10 KB [jl*100 + i]
    __shared__ __align__(16) float n1s[25 * HD];    // 6.4 KB

    // prefetch base rows (hides HBM latency behind staging)
    float bs[4];
    #pragma unroll
    for (int m = 0; m < 4; ++m) {
        const int jl = w + 8 * m;
        bs[m] = (jl < 25) ? baseo[(g * NPG + j0 + jl) * HD + hh] : 0.f;
    }

    {   // stage h slab (float4) + Wt chunk, coalesced
        const float4* ho4 = (const float4*)(h_old + g * NPG * HD);
        float4* hs4 = (float4*)hs;
        for (int idx = t; idx < NPG * HD / 4; idx += 512) hs4[idx] = ho4[idx];
        const float* wsrc = Wt + g * (NPG * NPG) + j0 * NPG;
        for (int idx = t; idx < 2500; idx += 512) wr[idx] = wsrc[idx];
    }
    __syncthreads();        // the only barrier in K2

    // phase 1: n1[j][hh] = sum_i Wt[j][i] * h[i][hh]   (wave-local rows)
    float acc[4];
    #pragma unroll
    for (int m = 0; m < 4; ++m) acc[m] = 0.f;
    for (int ib = 0; ib < 25; ++ib) {
        const float h0 = hs[(4 * ib + 0) * HD + hh];
        const float h1 = hs[(4 * ib + 1) * HD + hh];
        const float h2 = hs[(4 * ib + 2) * HD + hh];
        const float h3 = hs[(4 * ib + 3) * HD + hh];
        #pragma unroll
        for (int m = 0; m < 4; ++m) {
            const int jl = w + 8 * m;
            if (jl < 25) {
                const float4 wv = *(const float4*)&wr[jl * 100 + 4 * ib];
                acc[m] += wv.x * h0 + wv.y * h1 + wv.z * h2 + wv.w * h3;
            }
        }
    }
    #pragma unroll
    for (int m = 0; m < 4; ++m) {
        const int jl = w + 8 * m;
        if (jl < 25) n1s[jl * HD + hh] = acc[m];
    }
    // no barrier: phase 2 reads only this wave's own n1s rows

    const float l2bv = l2_b[hh];
    float v[4];
    #pragma unroll
    for (int m = 0; m < 4; ++m) v[m] = bs[m] + l2bv;
    for (int ib = 0; ib < 16; ++ib) {
        const float w0 = l2_w[(4 * ib + 0) * HD + hh];
        const float w1 = l2_w[(4 * ib + 1) * HD + hh];
        const float w2 = l2_w[(4 * ib + 2) * HD + hh];
        const float w3 = l2_w[(4 * ib + 3) * HD + hh];
        #pragma unroll
        for (int m = 0; m < 4; ++m) {
            const int jl = w + 8 * m;
            if (jl < 25) {
                const float4 x4 = *(const float4*)&n1s[jl * HD + 4 * ib];
                v[m] += x4.x * w0 + x4.y * w1 + x4.z * w2 + x4.w * w3;
            }
        }
    }
    #pragma unroll
    for (int m = 0; m < 4; ++m) {
        const int jl = w + 8 * m;
        if (jl < 25) h_new[(g * NPG + j0 + jl) * HD + hh] = fmaxf(v[m], 0.f);
    }
}

// ---------------------------------------------------------------------------
// K3: tail. block = (group, 25-action half), grid 128, 512 thr.
// Waves 0-6: action chain (rows al = aw + 7m, wave-local, no barriers).
// Wave 7: stem/gb serial chain via shuffles, concurrent. 3 barriers total.
// ---------------------------------------------------------------------------
__global__ __launch_bounds__(512)
void k_tail(const float* __restrict__ hfin, const int* __restrict__ actions,
            fcp t5_w, fcp t5_b, fcp t6_w, fcp t6_b,
            fcp t7_1_w, fcp t7_1_b, fcp t7_2_w, fcp t7_2_b,
            fcp t9_1_w, fcp t9_1_b, fcp t9_2_w, fcp t9_2_b,
            float* __restrict__ out)
{
    const int g    = blockIdx.x >> 1;
    const int half = blockIdx.x & 1;
    const int t    = threadIdx.x;
    const int hh   = t & 63;
    const int aw   = t >> 6;        // wave 0..7

    __shared__ __align__(16) float hsb[NPG * HD];   // 25.6 KB
    __shared__ __align__(16) float hsum[25 * HD];   // ha -> r2 (wave-local rows)
    __shared__ __align__(16) float r1s[25 * HD];
    __shared__ __align__(16) float awk[8 * HD];     // mean partials
    __shared__ float gbuf[HD];

    // prefetch action indices (hides latency behind staging)
    int a0r[4], a1r[4];
    #pragma unroll
    for (int m = 0; m < 4; ++m) {
        const int al = aw + 7 * m;          // waves 0-6 own action rows
        a0r[m] = 0; a1r[m] = 0;
        if (aw < 7 && al < 25) {
            const int a = g * NACT + half * 25 + al;
            a0r[m] = actions[a * 2 + 0];
            a1r[m] = actions[a * 2 + 1];
        }
    }

    {   // stage h slab (float4, coalesced)
        const float4* hg4 = (const float4*)(hfin + g * NPG * HD);
        float4* hs4 = (float4*)hsb;
        for (int idx = t; idx < NPG * HD / 4; idx += 512) hs4[idx] = hg4[idx];
    }
    __syncthreads();                        // barrier 1: hsb staged

    {   // mean partials (all 8 waves)
        float m = 0.f;
        for (int j = aw; j < NPG; j += 8) m += hsb[j * HD + hh];
        awk[aw * HD + hh] = m;
    }
    // ha = h[a0]+h[a1] (wave-local rows)
    #pragma unroll
    for (int m = 0; m < 4; ++m) {
        const int al = aw + 7 * m;
        if (aw < 7 && al < 25)
            hsum[al * HD + hh] = hsb[a0r[m] * HD + hh] + hsb[a1r[m] * HD + hh];
    }
    __syncthreads();                        // barrier 2: awk ready for wave 7

    if (aw == 7) {   // stem chain, concurrent with waves 0-6 below
        float ml = 0.f;
        #pragma unroll
        for (int ww = 0; ww < 8; ++ww) ml += awk[ww * HD + hh];
        ml *= (1.f / NPG);
        float s = t6_b[hh];
        #pragma unroll 8
        for (int q = 0; q < HD; ++q) s += __shfl(ml, q, 64) * t6_w[q * HD + hh];
        s = fmaxf(s, 0.f);
        float gb = t9_1_b[hh];
        #pragma unroll 8
        for (int q = 0; q < HD; ++q) gb += __shfl(s, q, 64) * t9_1_w[q * HD + hh];
        gbuf[hh] = gb;
    } else {
        // r1 = relu(ha @ t7_1_w + 2*b71)   (wave-local rows, q-outer weights)
        const float b71 = 2.f * t7_1_b[hh];
        float r[4];
        #pragma unroll
        for (int m = 0; m < 4; ++m) r[m] = b71;
        for (int ib = 0; ib < 16; ++ib) {
            const float w0 = t7_1_w[(4 * ib + 0) * HD + hh];
            const float w1 = t7_1_w[(4 * ib + 1) * HD + hh];
            const float w2 = t7_1_w[(4 * ib + 2) * HD + hh];
            const float w3 = t7_1_w[(4 * ib + 3) * HD + hh];
            #pragma unroll
            for (int m = 0; m < 4; ++m) {
                const int al = aw + 7 * m;
                if (al < 25) {
                    const float4 x4 = *(const float4*)&hsum[al * HD + 4 * ib];
                    r[m] += x4.x * w0 + x4.y * w1 + x4.z * w2 + x4.w * w3;
                }
            }
        }
        #pragma unroll
        for (int m = 0; m < 4; ++m) {
            const int al = aw + 7 * m;
            if (al < 25) r1s[al * HD + hh] = fmaxf(r[m], 0.f);
        }
        // r2 = relu(r1 @ t7_2_w + b72) -> hsum (same wave-local rows)
        const float b72 = t7_2_b[hh];
        #pragma unroll
        for (int m = 0; m < 4; ++m) r[m] = b72;
        for (int ib = 0; ib < 16; ++ib) {
            const float w0 = t7_2_w[(4 * ib + 0) * HD + hh];
            const float w1 = t7_2_w[(4 * ib + 1) * HD + hh];
            const float w2 = t7_2_w[(4 * ib + 2) * HD + hh];
            const float w3 = t7_2_w[(4 * ib + 3) * HD + hh];
            #pragma unroll
            for (int m = 0; m < 4; ++m) {
                const int al = aw + 7 * m;
                if (al < 25) {
                    const float4 x4 = *(const float4*)&r1s[al * HD + 4 * ib];
                    r[m] += x4.x * w0 + x4.y * w1 + x4.z * w2 + x4.w * w3;
                }
            }
        }
        #pragma unroll
        for (int m = 0; m < 4; ++m) {
            const int al = aw + 7 * m;
            if (al < 25) hsum[al * HD + hh] = fmaxf(r[m], 0.f);
        }
    }
    __syncthreads();                        // barrier 3: gbuf ready

    if (aw < 7) {
        // u = r2 @ t9_2_w + b92 ; q = relu(gb+u) ; Q = q . t5_w + t5_b
        const float b92  = t9_2_b[hh];
        const float t5wv = t5_w[hh];
        const float t5bv = t5_b[0];
        const float gbv  = gbuf[hh];
        float u[4];
        #pragma unroll
        for (int m = 0; m < 4; ++m) u[m] = b92;
        for (int ib = 0; ib < 16; ++ib) {
            const float w0 = t9_2_w[(4 * ib + 0) * HD + hh];
            const float w1 = t9_2_w[(4 * ib + 1) * HD + hh];
            const float w2 = t9_2_w[(4 * ib + 2) * HD + hh];
            const float w3 = t9_2_w[(4 * ib + 3) * HD + hh];
            #pragma unroll
            for (int m = 0; m < 4; ++m) {
                const int al = aw + 7 * m;
                if (al < 25) {
                    const float4 x4 = *(const float4*)&hsum[al * HD + 4 * ib];
                    u[m] += x4.x * w0 + x4.y * w1 + x4.z * w2 + x4.w * w3;
                }
            }
        }
        #pragma unroll
        for (int m = 0; m < 4; ++m) {
            const int al = aw + 7 * m;
            float qv = fmaxf(gbv + u[m], 0.f) * t5wv;
            #pragma unroll
            for (int off = 32; off > 0; off >>= 1) qv += __shfl_xor(qv, off, 64);
            if (al < 25 && hh == 0) out[g * NACT + half * 25 + al] = qv + t5bv;
        }
    }
}

// ---------------------------------------------------------------------------
extern "C" void kernel_launch(void* const* d_in, const int* in_sizes, int n_in,
                              void* d_out, int out_size, void* d_ws, size_t ws_size,
                              hipStream_t stream)
{
    fcp label  = (fcp)d_in[0];
    fcp e_type = (fcp)d_in[1];
    fcp dvec   = (fcp)d_in[2];
    fcp l1_w   = (fcp)d_in[3];
    fcp l1_b   = (fcp)d_in[4];
    fcp l2_w   = (fcp)d_in[5];
    fcp l2_b   = (fcp)d_in[6];
    fcp t3_w   = (fcp)d_in[7];
    fcp t3_b   = (fcp)d_in[8];
    fcp t4_w   = (fcp)d_in[9];
    fcp t4_b   = (fcp)d_in[10];
    fcp t5_w   = (fcp)d_in[11];
    fcp t5_b   = (fcp)d_in[12];
    fcp t6_w   = (fcp)d_in[13];
    fcp t6_b   = (fcp)d_in[14];
    fcp t7_1_w = (fcp)d_in[15];
    fcp t7_1_b = (fcp)d_in[16];
    fcp t7_2_w = (fcp)d_in[17];
    fcp t7_2_b = (fcp)d_in[18];
    fcp t9_1_w = (fcp)d_in[19];
    fcp t9_1_b = (fcp)d_in[20];
    fcp t9_2_w = (fcp)d_in[21];
    fcp t9_2_b = (fcp)d_in[22];
    // d_in[23]=src, d_in[24]=dst -- topology derived analytically
    const int* actions = (const int*)d_in[25];

    // Workspace: Wt 2,560,000 B | base 1,638,400 | hA 1,638,400 | hB 1,638,400
    char* ws = (char*)d_ws;
    float* Wt   = (float*)(ws);
    float* base = (float*)(ws + 2560000);
    float* hA   = (float*)(ws + 2560000 + 1638400);
    float* hB   = (float*)(ws + 2560000 + 2 * 1638400);

    k_edge_base<<<dim3(NGRP * 4), dim3(512), 0, stream>>>(
        label, e_type, dvec, l1_w, l1_b, l2_b, t3_w, t3_b, t4_w, t4_b,
        Wt, base, hA);
    k_gnn_step<<<dim3(NGRP * 4), dim3(512), 0, stream>>>(Wt, base, hA, l2_w, l2_b, hB);
    k_gnn_step<<<dim3(NGRP * 4), dim3(512), 0, stream>>>(Wt, base, hB, l2_w, l2_b, hA);
    k_tail<<<dim3(NGRP * 2), dim3(512), 0, stream>>>(
        hA, actions, t5_w, t5_b, t6_w, t6_b, t7_1_w, t7_1_b, t7_2_w, t7_2_b,
        t9_1_w, t9_1_b, t9_2_w, t9_2_b, (float*)d_out);
}